// Round 2
// baseline (236.166 us; speedup 1.0000x reference)
//
#include <hip/hip_runtime.h>

// Problem constants (fixed by reference setup_inputs)
#define BN 32768              // batch
#define DN 1024               // feature dim
#define CN 256                // num classes
#define NSLICE 8              // row slices per class (slice id == bid&7 -> XCD id)
#define SROWS (BN / NSLICE)   // 4096 rows per slice
#define SCAP 56               // per-(class,slice) member cap: mean 16, sigma ~4 -> 10 sigma

__device__ __forceinline__ float dot4(float4 a, float4 b) {
    return a.x*b.x + a.y*b.y + a.z*b.z + a.w*b.w;
}

// ---------------------------------------------------------------------------
// K_SUM: 2048 blocks = 256 classes x 8 row-slices, 256 threads (4 waves).
// bid -> c = bid>>3, s = bid&7 (s tracks XCD under round-robin dispatch, so
// each XCD reads mostly its own 16 MB feature slab).
// Phases:
//  1) stage this slice's 4096 labels packed as bytes into 4 KB LDS
//  2) ballot-scan compaction -> ordered member list lm[] (global row ids),
//     list + count to global for k_finish
//  3) gather: wave w takes list positions p = w, w+4, ...: load full 4 KB
//     row, xor-shuffle row norm, write rnorm[row], accumulate x*rn
//  4) reduce 4 waves via stride-5-padded LDS atomics (conflict-free, proven
//     0 bank conflicts in round 0), then atomicAdd the 1024-float partial
//     into global sums[c] (8-way inter-slice contention, 2M atomics total).
// launch_bounds(256,8): 8 blocks/CU = 32 waves/CU (vs 16 in round 0).
// ---------------------------------------------------------------------------
__global__ void __launch_bounds__(256, 8) k_sum(const float4* __restrict__ x4,
                                                const int* __restrict__ labels,
                                                float* __restrict__ sums,
                                                float* __restrict__ rnorm,
                                                int* __restrict__ idx_part,
                                                int* __restrict__ cnt_part) {
    __shared__ unsigned int packed[SROWS / 4];   // 4 KB: 4 labels per word
    __shared__ int lm[SCAP];                     // ordered member rows (global ids)
    __shared__ int wcnt[4];
    __shared__ float fa[(DN / 4) * 5];           // 5 KB: 256 quads, stride-5 padded

    const int bid = blockIdx.x;
    const int c = bid >> 3;
    const int s = bid & 7;
    const int t = threadIdx.x;
    const int row0 = s * SROWS;

    // ---- stage labels slice (1024 int4 words / 256 thr = 4 each) ----
    {
        const int4* l4 = (const int4*)labels + s * (SROWS / 16);
        for (int w = t; w < SROWS / 4; w += 256) {
            const int4 v = ((const int4*)((const int*)labels + row0))[w];
            packed[w] = (unsigned int)(v.x & 255)
                      | ((unsigned int)(v.y & 255) << 8)
                      | ((unsigned int)(v.z & 255) << 16)
                      | ((unsigned int)(v.w & 255) << 24);
        }
        (void)l4;
    }
    for (int i = t; i < (DN / 4) * 5; i += 256) fa[i] = 0.0f;
    __syncthreads();

    const int wave = t >> 6, lane = t & 63;
    const unsigned long long lt = (lane == 0) ? 0ull : (~0ull >> (64 - lane));
    const int ch0 = wave * 16, ch1 = ch0 + 16;   // 16 chunks of 64 rows per wave

    // ---- pass 1: count ----
    int cnt = 0;
    for (int ch = ch0; ch < ch1; ++ch) {
        const int gi = ch * 64 + lane;
        const int lab = (packed[gi >> 2] >> ((gi & 3) * 8)) & 255;
        cnt += __popcll(__ballot(lab == c));
    }
    if (lane == 0) wcnt[wave] = cnt;
    __syncthreads();

    int base = 0, ntot = 0;
    for (int w2 = 0; w2 < 4; ++w2) {
        const int v = wcnt[w2];
        if (w2 < wave) base += v;
        ntot += v;
    }

    // ---- pass 2: ordered member list (LDS + global for k_finish) ----
    for (int ch = ch0; ch < ch1; ++ch) {
        const int gi = ch * 64 + lane;
        const int lab = (packed[gi >> 2] >> ((gi & 3) * 8)) & 255;
        const bool pred = (lab == c);
        const unsigned long long mask = __ballot(pred);
        if (pred) {
            const int pos = base + __popcll(mask & lt);
            if (pos < SCAP) {
                const int grow = row0 + gi;
                lm[pos] = grow;
                idx_part[bid * SCAP + pos] = grow;
            }
        }
        base += __popcll(mask);
    }
    if (t == 0) cnt_part[bid] = ntot;
    __syncthreads();

    // ---- gather + row norm + scaled accumulate (1 row / wave-iteration) ----
    const int m = min(ntot, SCAP);
    float4 a0 = make_float4(0.f, 0.f, 0.f, 0.f), a1 = a0, a2 = a0, a3 = a0;
    for (int p = wave; p < m; p += 4) {
        const int row = lm[p];
        const float4* b4 = x4 + (size_t)row * 256;
        const float4 v0 = b4[lane];
        const float4 v1 = b4[lane + 64];
        const float4 v2 = b4[lane + 128];
        const float4 v3 = b4[lane + 192];
        float ss = dot4(v0, v0) + dot4(v1, v1) + dot4(v2, v2) + dot4(v3, v3);
#pragma unroll
        for (int off = 32; off; off >>= 1) ss += __shfl_xor(ss, off, 64);
        const float rn = 1.0f / fmaxf(sqrtf(ss), 1e-12f);
        if (lane == 0) rnorm[row] = rn;
        a0.x += v0.x * rn; a0.y += v0.y * rn; a0.z += v0.z * rn; a0.w += v0.w * rn;
        a1.x += v1.x * rn; a1.y += v1.y * rn; a1.z += v1.z * rn; a1.w += v1.w * rn;
        a2.x += v2.x * rn; a2.y += v2.y * rn; a2.z += v2.z * rn; a2.w += v2.w * rn;
        a3.x += v3.x * rn; a3.y += v3.y * rn; a3.z += v3.z * rn; a3.w += v3.w * rn;
    }

    // ---- reduce 4 waves into padded LDS (quad q at fa[5q..5q+3]) ----
    {
        const int q0 = lane, q1 = lane + 64, q2 = lane + 128, q3 = lane + 192;
        atomicAdd(&fa[5 * q0 + 0], a0.x); atomicAdd(&fa[5 * q0 + 1], a0.y);
        atomicAdd(&fa[5 * q0 + 2], a0.z); atomicAdd(&fa[5 * q0 + 3], a0.w);
        atomicAdd(&fa[5 * q1 + 0], a1.x); atomicAdd(&fa[5 * q1 + 1], a1.y);
        atomicAdd(&fa[5 * q1 + 2], a1.z); atomicAdd(&fa[5 * q1 + 3], a1.w);
        atomicAdd(&fa[5 * q2 + 0], a2.x); atomicAdd(&fa[5 * q2 + 1], a2.y);
        atomicAdd(&fa[5 * q2 + 2], a2.z); atomicAdd(&fa[5 * q2 + 3], a2.w);
        atomicAdd(&fa[5 * q3 + 0], a3.x); atomicAdd(&fa[5 * q3 + 1], a3.y);
        atomicAdd(&fa[5 * q3 + 2], a3.z); atomicAdd(&fa[5 * q3 + 3], a3.w);
    }
    __syncthreads();

    // ---- accumulate block partial into global sums[c] (device atomics) ----
    {
        float* dst = sums + (size_t)c * DN + 4 * t;
        atomicAdd(dst + 0, fa[5 * t + 0]);
        atomicAdd(dst + 1, fa[5 * t + 1]);
        atomicAdd(dst + 2, fa[5 * t + 2]);
        atomicAdd(dst + 3, fa[5 * t + 3]);
    }
}

// ---------------------------------------------------------------------------
// K_FINISH: one block per class. Read S = sums[c] (one quad per thread),
// ||S||^2 via block reduce, closed-form class contribution (n - ||S||^2/n)/D,
// then fused exclusion corrections: member row j (global index) gets a
// correction iff j < n; excluded member k = sic[j] (j-th ordered member of
// class c). ~0.5 corrections per class expected. Pre-scaled atomicAdd into
// out[0] (memset-zeroed) -- no separate finalize kernel.
// ---------------------------------------------------------------------------
__global__ void __launch_bounds__(256) k_finish(const float4* __restrict__ x4,
                                                const float* __restrict__ sums,
                                                const float* __restrict__ rnorm,
                                                const int* __restrict__ idx_part,
                                                const int* __restrict__ cnt_part,
                                                float* __restrict__ out) {
    __shared__ int sic[NSLICE * SCAP];   // 448 ints: ordered member list
    __shared__ int scc[NSLICE], spre[NSLICE], sn, snn;
    __shared__ float wred[4];
    __shared__ float4 cred[4];

    const int c = blockIdx.x;
    const int t = threadIdx.x;
    const int wave = t >> 6, lane = t & 63;

    // per-slice counts -> true n, capped prefix (LDS: avoids runtime-indexed
    // per-thread arrays spilling to scratch, rule #20)
    if (t == 0) {
        int n = 0, nn = 0;
        for (int i2 = 0; i2 < NSLICE; ++i2) {
            const int cv = cnt_part[c * NSLICE + i2];
            n += cv;
            const int cc = min(cv, SCAP);
            scc[i2] = cc;
            spre[i2] = nn;
            nn += cc;
        }
        sn = n; snn = nn;
    }
    __syncthreads();
    const int n = sn, nn = snn;
    if (n < 2) return;   // contribution 0, no exclusions counted

    // S: thread t holds quad t
    const float4 Sq = ((const float4*)sums)[(size_t)c * 256 + t];

    // ||S||^2 partial
    float d = dot4(Sq, Sq);
#pragma unroll
    for (int off = 32; off; off >>= 1) d += __shfl_xor(d, off, 64);
    if (lane == 0) wred[wave] = d;

    // assemble ordered member list: slices are ascending global-row ranges,
    // within-slice lists ascend -> concatenation is ordered by global index
    for (int u = t; u < NSLICE * SCAP; u += 256) {
        const int s2i = u / SCAP;
        const int r = u - s2i * SCAP;
        if (r < scc[s2i]) sic[spre[s2i] + r] = idx_part[(c * NSLICE + s2i) * SCAP + r];
    }
    __syncthreads();

    const float s2 = wred[0] + wred[1] + wred[2] + wred[3];
    const int nlim = min(n, nn);   // == n (slices never overflow SCAP)

    // ---- exclusion corrections (block-uniform control flow) ----
    float dacc = 0.0f;   // only t==0's copy is used
    for (int p = 0; p < nn; ++p) {
        const int j = sic[p];
        if (j >= nlim) continue;         // no exclusion for this member
        const int k = sic[j];            // j-th ordered member of class c
        const float4 xi = x4[(size_t)j * 256 + t];
        const float4 xk = x4[(size_t)k * 256 + t];
        float d0 = dot4(xi, Sq);
        float d1 = dot4(xi, xk);
        float d2 = dot4(xk, Sq);
        float d3 = dot4(xk, xk);
#pragma unroll
        for (int off = 32; off; off >>= 1) {
            d0 += __shfl_xor(d0, off, 64);
            d1 += __shfl_xor(d1, off, 64);
            d2 += __shfl_xor(d2, off, 64);
            d3 += __shfl_xor(d3, off, 64);
        }
        if (lane == 0) cred[wave] = make_float4(d0, d1, d2, d3);
        __syncthreads();
        if (t == 0) {
            const float xiS  = cred[0].x + cred[1].x + cred[2].x + cred[3].x;
            const float xixk = cred[0].y + cred[1].y + cred[2].y + cred[3].y;
            const float xkS  = cred[0].z + cred[1].z + cred[2].z + cred[3].z;
            const float xkxk = cred[0].w + cred[1].w + cred[2].w + cred[3].w;
            const float rni = rnorm[j], rnk = rnorm[k];
            const float fiS  = rni * xiS;
            const float fifk = rni * rnk * xixk;
            const float Sfk  = rnk * xkS;
            const float fk2  = rnk * rnk * xkxk;
            const float nf = (float)n;
            const float dd = nf - 1.0f;
            const float naive = -2.0f * fiS / nf + s2 / (nf * nf);
            const float corr  = -2.0f * (fiS - fifk) / dd + (s2 - 2.0f * Sfk + fk2) / (dd * dd);
            dacc += corr - naive;
        }
        __syncthreads();   // protect cred reuse next iteration
    }

    if (t == 0) {
        const float nf = (float)n;
        const float total = (nf - s2 / nf) + dacc;   // class contribution + deltas
        atomicAdd(out, total * (1.0f / DN) * (0.0005f / (float)BN));
    }
}

extern "C" void kernel_launch(void* const* d_in, const int* in_sizes, int n_in,
                              void* d_out, int out_size, void* d_ws, size_t ws_size,
                              hipStream_t stream) {
    const float4* x4 = (const float4*)d_in[0];
    const int* labels = (const int*)d_in[1];
    float* out = (float*)d_out;

    // ws layout (bytes) -- total 1,646,592 <= 1,705,988 proven available:
    char* ws = (char*)d_ws;
    float* sums     = (float*)(ws + 0);          // 256*1024 f  -> 1048576
    float* rnorm    = (float*)(ws + 1048576);    // 32768 f     -> 1179648
    int*   idx_part = (int*)  (ws + 1179648);    // 2048*56 i   -> 1638400
    int*   cnt_part = (int*)  (ws + 1638400);    // 2048 i      -> 1646592

    hipMemsetAsync(sums, 0, (size_t)CN * DN * sizeof(float), stream);
    hipMemsetAsync(out, 0, sizeof(float), stream);
    k_sum<<<CN * NSLICE, 256, 0, stream>>>(x4, labels, sums, rnorm, idx_part, cnt_part);
    k_finish<<<CN, 256, 0, stream>>>(x4, sums, rnorm, idx_part, cnt_part, out);
}

// Round 3
// 219.639 us; speedup vs baseline: 1.0752x; 1.0752x over previous
//
#include <hip/hip_runtime.h>

// Problem constants (fixed by reference setup_inputs)
#define BN 32768      // batch
#define DN 1024       // feature dim
#define CN 256        // num classes
#define RCAP 320      // max class size tracked (counts ~128 +/- 11; 320 = ~17 sigma)

__device__ __forceinline__ float dot4(float4 a, float4 b) {
    return a.x*b.x + a.y*b.y + a.z*b.z + a.w*b.w;
}

// ---------------------------------------------------------------------------
// K_ALL: one block (1024 thr / 16 waves) per class. Fully fused:
//  1) stage all labels to LDS packed as bytes (32 KB), ballot-scan compaction
//     -> ordered member list sic[] (block-local only)
//  2) gather, 2 rows per wave-iteration (8 dwordx4 in flight, two independent
//     shuffle-reduce norm chains): write rn to LDS rnl[pos], accumulate x*rn
//     into wave-private regs (features read EXACTLY ONCE from HBM)
//  3) block-reduce wave accumulators via stride-5-padded LDS atomics
//     (proven conflict-free, 0 SQ_LDS_BANK_CONFLICT); S stays in registers
//     of threads t<256
//  4) fused exclusion corrections: member at position p (global row j=sic[p])
//     has an exclusion iff j < n; excluded member k = sic[j]. ~0.5 per class,
//     ~130 device-wide. Rows j,k re-read (L1/L2-hot). Norms from LDS rnl.
//  5) single pre-scaled atomicAdd of (class contribution + deltas) into out.
// No global intermediates: 2 dispatches total (4 B memset + k_all).
// ---------------------------------------------------------------------------
__global__ void __launch_bounds__(1024) k_all(const float4* __restrict__ x4,
                                              const int* __restrict__ labels,
                                              float* __restrict__ out) {
    __shared__ unsigned int packed[BN / 4];   // 32 KB: 4 labels per word
    __shared__ int sic[RCAP];                 // ordered member list (global rows)
    __shared__ float rnl[RCAP];               // 1/||x_row|| per member position
    __shared__ int wcnt[16];
    __shared__ float fa[(DN / 4) * 5];        // 5 KB, stride-5 padded quads
    __shared__ float wred[4];
    __shared__ float4 cred[4];

    const int c = blockIdx.x;
    const int t = threadIdx.x;

    // ---- stage labels (8192 words / 1024 thr = 2 int4 loads each) ----
    for (int w = t; w < BN / 4; w += 1024) {
        const int4 v = ((const int4*)labels)[w];
        packed[w] = (unsigned int)(v.x & 255)
                  | ((unsigned int)(v.y & 255) << 8)
                  | ((unsigned int)(v.z & 255) << 16)
                  | ((unsigned int)(v.w & 255) << 24);
    }
    for (int i = t; i < (DN / 4) * 5; i += 1024) fa[i] = 0.0f;
    __syncthreads();

    const int wave = t >> 6, lane = t & 63;
    const unsigned long long lt = (lane == 0) ? 0ull : (~0ull >> (64 - lane));
    const int ch0 = wave * 32, ch1 = ch0 + 32;  // 32 chunks of 64 per wave

    // ---- pass 1: count ----
    int cnt = 0;
    for (int ch = ch0; ch < ch1; ++ch) {
        const int gi = ch * 64 + lane;
        const int lab = (packed[gi >> 2] >> ((gi & 3) * 8)) & 255;
        cnt += __popcll(__ballot(lab == c));
    }
    if (lane == 0) wcnt[wave] = cnt;
    __syncthreads();

    int base = 0, ntot = 0;
    for (int w2 = 0; w2 < 16; ++w2) {
        const int v = wcnt[w2];
        if (w2 < wave) base += v;
        ntot += v;
    }

    // ---- pass 2: ordered member list (LDS only) ----
    for (int ch = ch0; ch < ch1; ++ch) {
        const int gi = ch * 64 + lane;
        const int lab = (packed[gi >> 2] >> ((gi & 3) * 8)) & 255;
        const bool pred = (lab == c);
        const unsigned long long mask = __ballot(pred);
        if (pred) {
            const int pos = base + __popcll(mask & lt);
            if (pos < RCAP) sic[pos] = gi;
        }
        base += __popcll(mask);
    }
    __syncthreads();

    // ---- gather + row norms + scaled accumulate, 2 rows / wave-iteration ----
    const int nn = min(ntot, RCAP);
    float4 a0 = make_float4(0.f, 0.f, 0.f, 0.f), a1 = a0, a2 = a0, a3 = a0;
    for (int r = wave; r < nn; r += 32) {
        const int rowA = sic[r];
        const bool hasB = (r + 16) < nn;
        const int rowB = hasB ? sic[r + 16] : rowA;
        const float4* bA = x4 + (size_t)rowA * 256;
        const float4* bB = x4 + (size_t)rowB * 256;
        const float4 uA0 = bA[lane];
        const float4 uA1 = bA[lane + 64];
        const float4 uA2 = bA[lane + 128];
        const float4 uA3 = bA[lane + 192];
        const float4 uB0 = bB[lane];
        const float4 uB1 = bB[lane + 64];
        const float4 uB2 = bB[lane + 128];
        const float4 uB3 = bB[lane + 192];
        float sA = dot4(uA0, uA0) + dot4(uA1, uA1) + dot4(uA2, uA2) + dot4(uA3, uA3);
        float sB = dot4(uB0, uB0) + dot4(uB1, uB1) + dot4(uB2, uB2) + dot4(uB3, uB3);
#pragma unroll
        for (int off = 32; off; off >>= 1) {
            sA += __shfl_xor(sA, off, 64);
            sB += __shfl_xor(sB, off, 64);
        }
        const float rnA  = 1.0f / fmaxf(sqrtf(sA), 1e-12f);
        const float rnBr = 1.0f / fmaxf(sqrtf(sB), 1e-12f);
        const float rnB  = hasB ? rnBr : 0.0f;   // zero-scale the duplicated tail row
        if (lane == 0) {
            rnl[r] = rnA;
            if (hasB) rnl[r + 16] = rnBr;
        }
        a0.x += uA0.x * rnA + uB0.x * rnB; a0.y += uA0.y * rnA + uB0.y * rnB;
        a0.z += uA0.z * rnA + uB0.z * rnB; a0.w += uA0.w * rnA + uB0.w * rnB;
        a1.x += uA1.x * rnA + uB1.x * rnB; a1.y += uA1.y * rnA + uB1.y * rnB;
        a1.z += uA1.z * rnA + uB1.z * rnB; a1.w += uA1.w * rnA + uB1.w * rnB;
        a2.x += uA2.x * rnA + uB2.x * rnB; a2.y += uA2.y * rnA + uB2.y * rnB;
        a2.z += uA2.z * rnA + uB2.z * rnB; a2.w += uA2.w * rnA + uB2.w * rnB;
        a3.x += uA3.x * rnA + uB3.x * rnB; a3.y += uA3.y * rnA + uB3.y * rnB;
        a3.z += uA3.z * rnA + uB3.z * rnB; a3.w += uA3.w * rnA + uB3.w * rnB;
    }

    // ---- reduce 16 waves into padded LDS (quad q at fa[5q..5q+3]) ----
    {
        const int q0 = lane, q1 = lane + 64, q2 = lane + 128, q3 = lane + 192;
        atomicAdd(&fa[5 * q0 + 0], a0.x); atomicAdd(&fa[5 * q0 + 1], a0.y);
        atomicAdd(&fa[5 * q0 + 2], a0.z); atomicAdd(&fa[5 * q0 + 3], a0.w);
        atomicAdd(&fa[5 * q1 + 0], a1.x); atomicAdd(&fa[5 * q1 + 1], a1.y);
        atomicAdd(&fa[5 * q1 + 2], a1.z); atomicAdd(&fa[5 * q1 + 3], a1.w);
        atomicAdd(&fa[5 * q2 + 0], a2.x); atomicAdd(&fa[5 * q2 + 1], a2.y);
        atomicAdd(&fa[5 * q2 + 2], a2.z); atomicAdd(&fa[5 * q2 + 3], a2.w);
        atomicAdd(&fa[5 * q3 + 0], a3.x); atomicAdd(&fa[5 * q3 + 1], a3.y);
        atomicAdd(&fa[5 * q3 + 2], a3.z); atomicAdd(&fa[5 * q3 + 3], a3.w);
    }
    __syncthreads();

    // ---- S (quad per thread t<256) and ||S||^2 ----
    float4 Sq = make_float4(0.f, 0.f, 0.f, 0.f);
    float d = 0.0f;
    if (t < 256) {
        Sq.x = fa[5 * t + 0]; Sq.y = fa[5 * t + 1];
        Sq.z = fa[5 * t + 2]; Sq.w = fa[5 * t + 3];
        d = dot4(Sq, Sq);
    }
    if (wave < 4) {
#pragma unroll
        for (int off = 32; off; off >>= 1) d += __shfl_xor(d, off, 64);
        if (lane == 0) wred[wave] = d;
    }
    __syncthreads();

    const int n = ntot;
    if (n >= 2) {                       // uniform across block
        const float s2 = wred[0] + wred[1] + wred[2] + wred[3];
        const int nlim = min(n, nn);
        float dacc = 0.0f;              // only t==0's copy is used
        for (int p = 0; p < nn; ++p) {
            const int j = sic[p];
            if (j >= nlim) continue;    // this member has no exclusion (uniform)
            const int k = sic[j];       // j-th ordered member of class c
            if (t < 256) {
                const float4 xi = x4[(size_t)j * 256 + t];
                const float4 xk = x4[(size_t)k * 256 + t];
                float d0 = dot4(xi, Sq);
                float d1 = dot4(xi, xk);
                float d2 = dot4(xk, Sq);
                float d3 = dot4(xk, xk);
#pragma unroll
                for (int off = 32; off; off >>= 1) {
                    d0 += __shfl_xor(d0, off, 64);
                    d1 += __shfl_xor(d1, off, 64);
                    d2 += __shfl_xor(d2, off, 64);
                    d3 += __shfl_xor(d3, off, 64);
                }
                if (lane == 0) cred[wave] = make_float4(d0, d1, d2, d3);
            }
            __syncthreads();
            if (t == 0) {
                const float xiS  = cred[0].x + cred[1].x + cred[2].x + cred[3].x;
                const float xixk = cred[0].y + cred[1].y + cred[2].y + cred[3].y;
                const float xkS  = cred[0].z + cred[1].z + cred[2].z + cred[3].z;
                const float xkxk = cred[0].w + cred[1].w + cred[2].w + cred[3].w;
                const float rni = rnl[p], rnk = rnl[j];
                const float fiS  = rni * xiS;
                const float fifk = rni * rnk * xixk;
                const float Sfk  = rnk * xkS;
                const float fk2  = rnk * rnk * xkxk;
                const float nf = (float)n;
                const float dd = nf - 1.0f;
                const float naive = -2.0f * fiS / nf + s2 / (nf * nf);
                const float corr  = -2.0f * (fiS - fifk) / dd
                                  + (s2 - 2.0f * Sfk + fk2) / (dd * dd);
                dacc += corr - naive;
            }
            __syncthreads();   // protect cred reuse next iteration
        }
        if (t == 0) {
            const float nf = (float)n;
            const float total = (nf - s2 / nf) + dacc;
            atomicAdd(out, total * (1.0f / DN) * (0.0005f / (float)BN));
        }
    }
}

extern "C" void kernel_launch(void* const* d_in, const int* in_sizes, int n_in,
                              void* d_out, int out_size, void* d_ws, size_t ws_size,
                              hipStream_t stream) {
    const float4* x4 = (const float4*)d_in[0];
    const int* labels = (const int*)d_in[1];
    float* out = (float*)d_out;

    hipMemsetAsync(out, 0, sizeof(float), stream);
    k_all<<<CN, 1024, 0, stream>>>(x4, labels, out);
}